// Round 4
// baseline (324.668 us; speedup 1.0000x reference)
//
#include <hip/hip_runtime.h>
#include <hip/hip_bf16.h>

// Shapes (fixed): B=4, C=256, H=W=128 -> HW=16384, C8=32, L=1024
typedef __attribute__((ext_vector_type(8))) short short8;   // 8 bf16 (MFMA A/B frag)
typedef __attribute__((ext_vector_type(4))) float f32x4;    // MFMA C/D frag

__device__ __forceinline__ unsigned short f2bf(float x) {
    unsigned int u = __float_as_uint(x);
    u += 0x7fffu + ((u >> 16) & 1u);      // RNE
    return (unsigned short)(u >> 16);
}

// XOR-swizzle of 16B chunks within a 128-halfword row: conflict-free b128
// reads, <=2-way (free) b64 writes. key = row & 15.
#define SWZ(row, col) (((((col) >> 3) ^ ((row) & 15)) << 3) | ((col) & 7))

// ---------------------------------------------------------------------------
// Kernel 1 (fused wide launch): blocks 0..1023 = Q projection,
// blocks 1024..5119 = 4x4 adaptive avg pool. Both are independent streaming
// ops; one dispatch removes a serial latency segment from the chain.
// ---------------------------------------------------------------------------
__global__ __launch_bounds__(256) void k_pre(const float* __restrict__ query,
        const float* __restrict__ Wq, const float* __restrict__ bq,
        const float* __restrict__ kv,
        unsigned short* __restrict__ Qfb, float* __restrict__ pooled) {
    int t = threadIdx.x;
    if (blockIdx.x < 1024) {
        // ---- Q projection -> bf16 Qfb (B, HW, 32) ----
        int ln = t & 63;
        int o0 = __builtin_amdgcn_readfirstlane((t >> 6) * 8);
        int b = blockIdx.x >> 8;
        int n = (blockIdx.x & 255) * 64 + ln;
        const float* src = query + (size_t)b * 4194304 + n;
        float acc[8];
#pragma unroll
        for (int j = 0; j < 8; ++j) acc[j] = bq[o0 + j];
        for (int c0 = 0; c0 < 256; c0 += 4) {
            float v0 = src[(size_t)(c0 + 0) * 16384];
            float v1 = src[(size_t)(c0 + 1) * 16384];
            float v2 = src[(size_t)(c0 + 2) * 16384];
            float v3 = src[(size_t)(c0 + 3) * 16384];
#pragma unroll
            for (int j = 0; j < 8; ++j) {
                f32x4 w = *(const f32x4*)&Wq[(o0 + j) * 256 + c0];   // wave-uniform
                acc[j] += w[0] * v0 + w[1] * v1 + w[2] * v2 + w[3] * v3;
            }
        }
        short8 pk;
#pragma unroll
        for (int j = 0; j < 8; ++j) pk[j] = (short)f2bf(acc[j]);
        *(short8*)&Qfb[((size_t)b * 16384 + n) * 32 + o0] = pk;
    } else {
        // ---- 4x4 avg pool (B,C,128,128) -> (B,C,32,32) ----
        int idx = (blockIdx.x - 1024) * 256 + t;
        int pw = idx & 31;
        int ph = (idx >> 5) & 31;
        int bc = idx >> 10;
        const f32x4* row = (const f32x4*)(kv + ((size_t)bc * 128 + ph * 4) * 128);
        float s = 0.f;
#pragma unroll
        for (int i = 0; i < 4; ++i) {
            f32x4 v = row[i * 32 + pw];
            s += v[0] + v[1] + v[2] + v[3];
        }
        pooled[idx] = s * (1.f / 16.f);
    }
}

// ---------------------------------------------------------------------------
// Kernel 2: K,V projections. 1152 blocks = b(4) x otile(18) x ltile(16).
// Thread: 4 output rows at one l; W reads wave-uniform -> scalar loads.
// Ktb bf16 (B,1024,32) transposed; Vb bf16 (B,256,1024).
// ---------------------------------------------------------------------------
__global__ __launch_bounds__(256) void k_kvproj(const float* __restrict__ pooled,
        const float* __restrict__ Wk, const float* __restrict__ bk,
        const float* __restrict__ Wv, const float* __restrict__ bv,
        unsigned short* __restrict__ Ktb, unsigned short* __restrict__ Vb) {
    int t = threadIdx.x;
    int lane = t & 63;
    int og = __builtin_amdgcn_readfirstlane(t >> 6);
    int blk = blockIdx.x;
    int b  = blk / 288;
    int r  = blk - b * 288;
    int ot = r >> 4;              // 0..17
    int lt = r & 15;              // 0..15
    int l  = lt * 64 + lane;
    int u0 = ot * 16 + og * 4;
    bool isK = (ot < 2);
    const float* Wbase = isK ? (Wk + (size_t)u0 * 256) : (Wv + (size_t)(u0 - 32) * 256);
    const float* bias  = isK ? (bk + u0) : (bv + (u0 - 32));
    const float* psrc  = pooled + (size_t)b * 256 * 1024 + l;

    float acc[4];
#pragma unroll
    for (int j = 0; j < 4; ++j) acc[j] = bias[j];
    for (int c0 = 0; c0 < 256; c0 += 4) {
        float p0 = psrc[(size_t)(c0 + 0) * 1024];
        float p1 = psrc[(size_t)(c0 + 1) * 1024];
        float p2 = psrc[(size_t)(c0 + 2) * 1024];
        float p3 = psrc[(size_t)(c0 + 3) * 1024];
#pragma unroll
        for (int j = 0; j < 4; ++j) {
            f32x4 w = *(const f32x4*)(Wbase + j * 256 + c0);   // wave-uniform
            acc[j] += w[0] * p0 + w[1] * p1 + w[2] * p2 + w[3] * p3;
        }
    }
    if (isK) {
        unsigned int k0 = (unsigned int)f2bf(acc[0]) | ((unsigned int)f2bf(acc[1]) << 16);
        unsigned int k1 = (unsigned int)f2bf(acc[2]) | ((unsigned int)f2bf(acc[3]) << 16);
        uint2 pk = {k0, k1};
        *(uint2*)&Ktb[((size_t)(b * 1024 + l)) * 32 + u0] = pk;
    } else {
#pragma unroll
        for (int j = 0; j < 4; ++j)
            Vb[((size_t)(b * 256 + u0 - 32 + j)) * 1024 + l] = f2bf(acc[j]);
    }
}

// ---------------------------------------------------------------------------
// Kernel 3: fused attention, TQ=64/block, 256 thr = 4 waves.
// 8 l-chunks of 128, software-pipelined; Pb double-buffered (XOR-swizzled).
// launch_bounds(256,3): cap unified regs <=170 so 3 blocks/CU can be resident
// (round-3 occupancy was ~21% => ~1.7 waves/SIMD; latency-stall dominated).
// ---------------------------------------------------------------------------
__global__ __launch_bounds__(256, 3) void k_attn(const unsigned short* __restrict__ Qfb,
        const unsigned short* __restrict__ Ktb, const unsigned short* __restrict__ Vb,
        const float* __restrict__ query, const float* __restrict__ gamma,
        float* __restrict__ out) {
    __shared__ unsigned short Pb[2][64][128];   // 32 KB, swizzled
    __shared__ float wsumL[4][16][4];           // [qt][q-low][wave]

    int t = threadIdx.x;
    int lane = t & 63, wv = t >> 6;
    int quad = lane >> 4, nl = lane & 15;
    int b = blockIdx.x >> 8;
    int n0 = (blockIdx.x & 255) * 64;

    // Q B-frags, resident all kernel: B[k=c][n=q]
    short8 qfrag[4];
#pragma unroll
    for (int qt = 0; qt < 4; ++qt)
        qfrag[qt] = *(const short8*)&Qfb[((size_t)b * 16384 + n0 + qt * 16 + nl) * 32 + quad * 8];

    f32x4 acc[4][4];
#pragma unroll
    for (int qt = 0; qt < 4; ++qt)
#pragma unroll
        for (int ct = 0; ct < 4; ++ct) { f32x4 z = {0.f, 0.f, 0.f, 0.f}; acc[qt][ct] = z; }
    float rsum[4] = {0.f, 0.f, 0.f, 0.f};

    const unsigned short* ktb = Ktb + (size_t)b * 1024 * 32;
    const unsigned short* vbb = Vb + (size_t)b * 256 * 1024;

    // S phase for chunk ch into buffer bi: wave owns l-slice [wv*32, wv*32+32)
#define S_PHASE(ch, bi)                                                          \
    {                                                                            \
        _Pragma("unroll")                                                        \
        for (int lt = 0; lt < 2; ++lt) {                                         \
            int lloc = wv * 32 + lt * 16;                                        \
            short8 kfrag = *(const short8*)&ktb[((size_t)((ch) * 128 + lloc + nl)) * 32 + quad * 8]; \
            _Pragma("unroll")                                                    \
            for (int qt = 0; qt < 4; ++qt) {                                     \
                f32x4 z = {0.f, 0.f, 0.f, 0.f};                                  \
                f32x4 s = __builtin_amdgcn_mfma_f32_16x16x32_bf16(kfrag, qfrag[qt], z, 0, 0, 0); \
                f32x4 p;                                                         \
                _Pragma("unroll")                                                \
                for (int i = 0; i < 4; ++i) p[i] = __expf(s[i]);                 \
                rsum[qt] += p[0] + p[1] + p[2] + p[3];                           \
                unsigned int w0 = (unsigned int)f2bf(p[0]) | ((unsigned int)f2bf(p[1]) << 16); \
                unsigned int w1 = (unsigned int)f2bf(p[2]) | ((unsigned int)f2bf(p[3]) << 16); \
                uint2 pk = {w0, w1};                                             \
                int prow = qt * 16 + nl;                                         \
                int pcol = lloc + quad * 4;                                      \
                *(uint2*)&Pb[bi][prow][SWZ(prow, pcol)] = pk;                    \
            }                                                                    \
        }                                                                        \
    }

    S_PHASE(0, 0)
    __syncthreads();

    for (int ch = 0; ch < 8; ++ch) {
        int bi = ch & 1;
        if (ch < 7) { S_PHASE(ch + 1, bi ^ 1) }
        // PV: wave owns c-range [64wv, 64wv+64)
#pragma unroll
        for (int ks = 0; ks < 4; ++ks) {
            int rcol = ((ks * 4 + quad) ^ nl) << 3;   // swizzled col
            short8 af[4];
#pragma unroll
            for (int qt = 0; qt < 4; ++qt)
                af[qt] = *(const short8*)&Pb[bi][qt * 16 + nl][rcol];
#pragma unroll
            for (int ct = 0; ct < 4; ++ct) {
                int c = wv * 64 + ct * 16 + nl;
                short8 bf = *(const short8*)&vbb[(size_t)c * 1024 + ch * 128 + ks * 32 + quad * 8];
#pragma unroll
                for (int qt = 0; qt < 4; ++qt)
                    acc[qt][ct] = __builtin_amdgcn_mfma_f32_16x16x32_bf16(af[qt], bf, acc[qt][ct], 0, 0, 0);
            }
        }
        __syncthreads();
    }

    // row-sum combine
#pragma unroll
    for (int qt = 0; qt < 4; ++qt) {
        float v = rsum[qt];
        v += __shfl_xor(v, 16);
        v += __shfl_xor(v, 32);
        if (lane < 16) wsumL[qt][nl][wv] = v;
    }
    __syncthreads();

    float inv[4][4];
#pragma unroll
    for (int qt = 0; qt < 4; ++qt)
#pragma unroll
        for (int r = 0; r < 4; ++r) {
            f32x4 sv = *(const f32x4*)wsumL[qt][quad * 4 + r];
            inv[qt][r] = 1.0f / (sv[0] + sv[1] + sv[2] + sv[3]);
        }

    float g0 = gamma[0];
    const float* qsrc = query + (size_t)b * 4194304;
    float* odst = out + (size_t)b * 4194304;
#pragma unroll
    for (int qt = 0; qt < 4; ++qt)
#pragma unroll
        for (int ct = 0; ct < 4; ++ct) {
            int c = wv * 64 + ct * 16 + nl;
            size_t base = (size_t)c * 16384 + n0 + qt * 16 + quad * 4;
            f32x4 qv = *(const f32x4*)(qsrc + base);
            f32x4 o;
#pragma unroll
            for (int r = 0; r < 4; ++r) o[r] = g0 * acc[qt][ct][r] * inv[qt][r] + qv[r];
            *(f32x4*)(odst + base) = o;
        }
}

extern "C" void kernel_launch(void* const* d_in, const int* in_sizes, int n_in,
                              void* d_out, int out_size, void* d_ws, size_t ws_size,
                              hipStream_t stream) {
    const float* query = (const float*)d_in[0];
    const float* kvf   = (const float*)d_in[1];
    const float* Wq    = (const float*)d_in[2];
    const float* bq    = (const float*)d_in[3];
    const float* Wk    = (const float*)d_in[4];
    const float* bk    = (const float*)d_in[5];
    const float* Wv    = (const float*)d_in[6];
    const float* bv    = (const float*)d_in[7];
    const float* gamma = (const float*)d_in[8];
    float* out = (float*)d_out;

    float* pooled       = (float*)d_ws;                        // 4 MB
    unsigned short* Ktb = (unsigned short*)(pooled + 1048576); // 256 KB
    unsigned short* Vb  = Ktb + 131072;                        // 2 MB
    unsigned short* Qfb = Vb + 1048576;                        // 4 MB

    k_pre   <<<dim3(5120), dim3(256), 0, stream>>>(query, Wq, bq, kvf, Qfb, pooled);
    k_kvproj<<<dim3(1152), dim3(256), 0, stream>>>(pooled, Wk, bk, Wv, bv, Ktb, Vb);
    k_attn  <<<dim3(1024), dim3(256), 0, stream>>>(Qfb, Ktb, Vb, query, gamma, out);
}